// Round 3
// baseline (484.181 us; speedup 1.0000x reference)
//
#include <hip/hip_runtime.h>
#include <hip/hip_bf16.h>
#include <stdint.h>

typedef int v4i __attribute__((ext_vector_type(4)));

#define BM 128
#define BN 128
#define BK 64
#define LDS_STRIDE 80  // multiple of 16 (ds_read_b128 alignment), 2-way banks = free

// ---------------- per-row dynamic quantization (x f32 -> int8 + scale) ----------------
__global__ __launch_bounds__(256) void quant_rows(
    const float* __restrict__ x, int8_t* __restrict__ xq,
    float* __restrict__ xs, int K) {
  const int row = blockIdx.x;
  const int t = threadIdx.x;
  const float4* src = (const float4*)(x + (size_t)row * K) + t * 4;
  float4 v[4];
  float m = 0.f;
#pragma unroll
  for (int i = 0; i < 4; ++i) {
    v[i] = src[i];
    m = fmaxf(m, fmaxf(fmaxf(fabsf(v[i].x), fabsf(v[i].y)),
                       fmaxf(fabsf(v[i].z), fabsf(v[i].w))));
  }
#pragma unroll
  for (int off = 1; off < 64; off <<= 1)
    m = fmaxf(m, __shfl_xor(m, off, 64));
  __shared__ float wmax[4];
  if ((t & 63) == 0) wmax[t >> 6] = m;
  __syncthreads();
  const float gm = fmaxf(fmaxf(wmax[0], wmax[1]), fmaxf(wmax[2], wmax[3]));
  const float scale = (gm + 1e-5f) / 127.0f;  // == ref x_scales
  if (t == 0) xs[row] = scale;
  unsigned packed[4];
#pragma unroll
  for (int i = 0; i < 4; ++i) {
    float fv[4] = {v[i].x, v[i].y, v[i].z, v[i].w};
    unsigned p = 0;
#pragma unroll
    for (int j = 0; j < 4; ++j) {
      int q = (int)rintf(fv[j] / scale);  // RNE, matches np.round
      q = max(-128, min(127, q));
      p |= (unsigned)(q & 0xff) << (8 * j);
    }
    packed[i] = p;
  }
  *(int4*)(xq + (size_t)row * K + t * 16) =
      make_int4((int)packed[0], (int)packed[1], (int)packed[2], (int)packed[3]);
}

// ---------------- W int32 [K][N] -> Wt int8 [N][K] (transpose + pack) ----------------
__global__ __launch_bounds__(256) void transpose_pack(
    const int* __restrict__ W32, int8_t* __restrict__ Wt, int K, int N) {
  __shared__ __align__(16) int8_t tile[64][LDS_STRIDE];
  const int t = threadIdx.x;
  const int n0 = blockIdx.x * 64;
  const int k0 = blockIdx.y * 64;
  const int ln = t & 63;  // n within tile (coalesced global dim)
  const int wv = t >> 6;  // wave id 0..3
#pragma unroll
  for (int it = 0; it < 16; ++it) {
    const int kk = wv * 16 + it;
    tile[ln][kk] = (int8_t)W32[(size_t)(k0 + kk) * N + n0 + ln];
  }
  __syncthreads();
  const int kb = wv * 16;  // 16-byte k-chunk
  const int4 v = *(const int4*)&tile[ln][kb];
  *(int4*)(Wt + (size_t)(n0 + ln) * K + k0 + kb) = v;
}

// ---------------- int8 GEMM (reg-staged, double-buffered) + fused dequant ----------------
__global__ __launch_bounds__(256) void gemm_i8(
    const int8_t* __restrict__ Xq, const int8_t* __restrict__ Wt,
    const float* __restrict__ xs, const float* __restrict__ wsc,
    const float* __restrict__ bias, float* __restrict__ C,
    int M, int N, int K) {
  __shared__ __align__(16) int8_t lA[2][BM * LDS_STRIDE];
  __shared__ __align__(16) int8_t lB[2][BN * LDS_STRIDE];
  const int t = threadIdx.x;
  const int lane = t & 63;
  const int wid = t >> 6;
  const size_t rowA0 = (size_t)blockIdx.y * BM;
  const size_t rowB0 = (size_t)blockIdx.x * BN;
  const int NT = K / BK;  // 64

  // staging: 512 16B-chunks per tile; thread t owns chunks t and t+256
  // chunk c -> row c>>2, k-byte (c&3)*16
  const int r0 = t >> 2, kb = (t & 3) * 16;
  const int8_t* gA0 = Xq + (rowA0 + r0) * K + kb;
  const int8_t* gA1 = gA0 + (size_t)64 * K;
  const int8_t* gB0 = Wt + (rowB0 + r0) * K + kb;
  const int8_t* gB1 = gB0 + (size_t)64 * K;
  const int oS0 = r0 * LDS_STRIDE + kb;
  const int oS1 = oS0 + 64 * LDS_STRIDE;

  // prologue: stage tile 0 into buf 0
  {
    int4 a0 = *(const int4*)gA0, a1 = *(const int4*)gA1;
    int4 b0 = *(const int4*)gB0, b1 = *(const int4*)gB1;
    *(int4*)&lA[0][oS0] = a0;
    *(int4*)&lA[0][oS1] = a1;
    *(int4*)&lB[0][oS0] = b0;
    *(int4*)&lB[0][oS1] = b1;
  }
  __syncthreads();

  v4i acc[4][4] = {};
  const int wr = wid >> 1, wc = wid & 1;
  const int fr = lane & 15;         // fragment row (A) / col (B)
  const int ks = (lane >> 4) * 16;  // k-slice byte offset

  for (int kt = 0; kt < NT; ++kt) {
    const int cur = kt & 1;
    int4 a0, a1, b0, b1;
    if (kt + 1 < NT) {  // issue next-tile loads early (latency under compute)
      const size_t ko = (size_t)(kt + 1) * BK;
      a0 = *(const int4*)(gA0 + ko);
      a1 = *(const int4*)(gA1 + ko);
      b0 = *(const int4*)(gB0 + ko);
      b1 = *(const int4*)(gB1 + ko);
    }
    v4i af[4], bf[4];
#pragma unroll
    for (int i = 0; i < 4; ++i) {
      af[i] = *(const v4i*)&lA[cur][(wr * 64 + i * 16 + fr) * LDS_STRIDE + ks];
      bf[i] = *(const v4i*)&lB[cur][(wc * 64 + i * 16 + fr) * LDS_STRIDE + ks];
    }
#pragma unroll
    for (int i = 0; i < 4; ++i)
#pragma unroll
      for (int j = 0; j < 4; ++j)
        acc[i][j] =
            __builtin_amdgcn_mfma_i32_16x16x64_i8(af[i], bf[j], acc[i][j], 0, 0, 0);
    if (kt + 1 < NT) {
      const int nb = cur ^ 1;
      *(int4*)&lA[nb][oS0] = a0;
      *(int4*)&lA[nb][oS1] = a1;
      *(int4*)&lB[nb][oS0] = b0;
      *(int4*)&lB[nb][oS1] = b1;
      __syncthreads();  // one barrier/iter: write(nb) visible; all reads of cur done
    }
  }

  // epilogue: dequant + bias -> bf16-round -> f32 store (ref returns f32)
  // C/D frag: col=lane&15, row=(lane>>4)*4+reg
#pragma unroll
  for (int i = 0; i < 4; ++i) {
    const int row_l = wr * 64 + i * 16 + (lane >> 4) * 4;
#pragma unroll
    for (int r = 0; r < 4; ++r) {
      const size_t row = rowA0 + row_l + r;
      const float xv = xs[row];
      float* crow = C + row * (size_t)N + rowB0;
#pragma unroll
      for (int j = 0; j < 4; ++j) {
        const int col_l = wc * 64 + j * 16 + fr;
        const float f =
            (float)acc[i][j][r] * xv * wsc[rowB0 + col_l] + bias[rowB0 + col_l];
        crow[col_l] = __bfloat162float(__float2bfloat16(f));
      }
    }
  }
}

extern "C" void kernel_launch(void* const* d_in, const int* in_sizes, int n_in,
                              void* d_out, int out_size, void* d_ws, size_t ws_size,
                              hipStream_t stream) {
  const int M = 4096, K = 4096, N = 16384;
  const float* x = (const float*)d_in[0];
  const int* W32 = (const int*)d_in[1];  // harness pushes integer inputs as int32
  const float* wsc = (const float*)d_in[2];
  const float* bias = (const float*)d_in[3];
  float* out = (float*)d_out;  // reference output dtype is float32 (bf16-rounded)

  // workspace layout: xs (16KB) | Xq (16MB) | Wt (64MB)
  float* xs = (float*)d_ws;
  int8_t* Xq = (int8_t*)d_ws + 16384;
  int8_t* Wt = (int8_t*)d_ws + 16384 + (size_t)M * K;

  transpose_pack<<<dim3(N / 64, K / 64), 256, 0, stream>>>(W32, Wt, K, N);
  quant_rows<<<M, 256, 0, stream>>>(x, Xq, xs, K);
  gemm_i8<<<dim3(N / BN, M / BM), 256, 0, stream>>>(Xq, Wt, xs, wsc, bias, out, M,
                                                    N, K);
}